// Round 4
// baseline (63.480 us; speedup 1.0000x reference)
//
#include <hip/hip_runtime.h>
#include <hip/hip_bf16.h>
#include <math.h>

#define BB 2
#define NN 512
#define KK 128
#define EE 768
#define NUM_EDGES 1536

// ---------------- fused kernel: one block per (b,i) row ----------------
// phase A: time-MLP (both encodings, redundant per block — tiny)
// phase B: per-j dist / delta_pos / affine x = mul*dist+bias
// phase C: 512x128 gaussian + time-add + pad-zero, float2 stores, f32 j-sum
// phase D: merge row GEMV 128 -> 768
__global__ __launch_bounds__(256) void edge_fused_kernel(
    const float* __restrict__ pos,
    const int* __restrict__ node_type_edge,
    const int* __restrict__ padding_mask,
    const int* __restrict__ mask_aa,
    const int* __restrict__ mask_pos,
    const int* __restrict__ time_pos,
    const float* __restrict__ means,
    const float* __restrict__ stds,
    const float* __restrict__ mul_w,
    const float* __restrict__ bias_w,
    const float* __restrict__ proj_w,   // [K,E]
    const float* __restrict__ proj_b,   // [E]
    const float* __restrict__ t_w1, const float* __restrict__ t_b1,
    const float* __restrict__ t_w2, const float* __restrict__ t_b2,
    float* __restrict__ out_ef,    // [B,N,N,K] f32
    float* __restrict__ out_merge, // [B,N,E]   f32
    float* __restrict__ out_dp)    // [B,N,N,3] f32
{
    __shared__ float e2[2][KK];
    __shared__ float h2[2][KK];
    __shared__ float tv[2][KK];          // tv[0]=2*t_enc(t_b), tv[1]=2*t_enc(0)
    __shared__ float xv[NN];             // mul*dist+bias per j
    __shared__ unsigned char fl[NN];     // bit0: mask_dist, bit1: padded j
    __shared__ float red[4 * KK];        // j-group partial sums

    const int bi = blockIdx.x;
    const int b = bi >> 9;
    const int i = bi & (NN - 1);
    const int tid = threadIdx.x;

    // ---- phase A: time encodings. threads 0..127 -> enc 0 (t=time_pos[b]),
    //      threads 128..255 -> enc 1 (t=0) ----
    {
        const int enc = tid >> 7;
        const int k = tid & 127;
        const float t = (enc == 0) ? (float)time_pos[b] : 0.0f;
        const int kk = k & 63;
        const float freq = __expf(-logf(10000.0f) * (float)kk * (1.0f / 64.0f));
        const float arg = t * freq;
        e2[enc][k] = (k < 64) ? cosf(arg) : sinf(arg);
        __syncthreads();

        float acc = t_b1[k];
#pragma unroll 8
        for (int r = 0; r < KK; ++r) acc += e2[enc][r] * t_w1[r * KK + k];
        h2[enc][k] = acc / (1.0f + __expf(-acc));   // SiLU
        __syncthreads();

        float acc2 = t_b2[k];
#pragma unroll 8
        for (int r = 0; r < KK; ++r) acc2 += h2[enc][r] * t_w2[r * KK + k];
        tv[enc][k] = 2.0f * acc2;
    }

    // ---- phase B: per-j quantities + delta_pos output ----
    const float pix = pos[(b * NN + i) * 3 + 0];
    const float piy = pos[(b * NN + i) * 3 + 1];
    const float piz = pos[(b * NN + i) * 3 + 2];
    const int maa_i  = mask_aa[b * NN + i];
    const int mpos_i = mask_pos[b * NN + i];

    for (int j = tid; j < NN; j += 256) {
        const float dx = pos[(b * NN + j) * 3 + 0] - pix;
        const float dy = pos[(b * NN + j) * 3 + 1] - piy;
        const float dz = pos[(b * NN + j) * 3 + 2] - piz;
        const float dist = sqrtf(dx * dx + dy * dy + dz * dz);
        const float invd = 1.0f / (dist + 1e-5f);
        const size_t dpo = ((size_t)bi * NN + j) * 3;
        out_dp[dpo + 0] = dx * invd;
        out_dp[dpo + 1] = dy * invd;
        out_dp[dpo + 2] = dz * invd;

        const int base = (bi * NN + j) * 2;
        int e0 = node_type_edge[base + 0];
        int e1 = node_type_edge[base + 1];
        if (maa_i)               e0 = 0;
        if (mask_aa[b * NN + j]) e1 = 0;
        const float mul  = mul_w[e0]  + mul_w[e1];
        const float bias = bias_w[e0] + bias_w[e1];
        xv[j] = mul * dist + bias;

        const int md  = (mpos_i | mask_pos[b * NN + j]) ? 1 : 0;
        const int pad = padding_mask[b * NN + j] ? 2 : 0;
        fl[j] = (unsigned char)(md | pad);
    }
    __syncthreads();

    // ---- phase C: per-thread k constants, sweep j ----
    const int k0 = (tid & 63) * 2;   // even k; this thread handles k0, k0+1
    const int jg = tid >> 6;         // j-group 0..3
    const float a = sqrtf(2.0f * 3.14159f);

    const float mean0 = means[k0];
    const float mean1 = means[k0 + 1];
    const float sd0 = fabsf(stds[k0]) + 0.01f;
    const float sd1 = fabsf(stds[k0 + 1]) + 0.01f;
    const float inv0 = 1.0f / sd0, inv1 = 1.0f / sd1;
    const float coef0 = 1.0f / (a * sd0), coef1 = 1.0f / (a * sd1);
    const float t2_0  = tv[0][k0];
    const float t2_1  = tv[0][k0 + 1];
    const float t02_0 = tv[1][k0];
    const float t02_1 = tv[1][k0 + 1];

    float s0 = 0.0f, s1 = 0.0f;
    const size_t efbase = (size_t)bi * NN * KK;

    for (int jj = 0; jj < NN / 4; ++jj) {
        const int j = jj * 4 + jg;
        const float x = xv[j];
        const unsigned char f = fl[j];

        const float u0 = (x - mean0) * inv0;
        const float u1 = (x - mean1) * inv1;
        float v0 = __expf(-0.5f * u0 * u0) * coef0 + ((f & 1) ? t2_0 : t02_0);
        float v1 = __expf(-0.5f * u1 * u1) * coef1 + ((f & 1) ? t2_1 : t02_1);
        if (f & 2) { v0 = 0.0f; v1 = 0.0f; }
        s0 += v0; s1 += v1;

        float2 pack; pack.x = v0; pack.y = v1;
        *reinterpret_cast<float2*>(&out_ef[efbase + (size_t)j * KK + k0]) = pack;
    }

    red[jg * KK + k0]     = s0;
    red[jg * KK + k0 + 1] = s1;
    __syncthreads();

    // ---- phase D: reduce sums, then merge GEMV ----
    if (tid < KK) {
        const int k = tid;
        red[k] = red[k] + red[KK + k] + red[2 * KK + k] + red[3 * KK + k];
    }
    __syncthreads();

    const bool pad_i = padding_mask[b * NN + i] != 0;
#pragma unroll
    for (int r = 0; r < 3; ++r) {
        const int e = tid + r * 256;
        float acc = proj_b[e];
#pragma unroll 16
        for (int k = 0; k < KK; ++k)
            acc += red[k] * proj_w[k * EE + e];
        out_merge[(size_t)bi * EE + e] = pad_i ? 0.0f : acc;
    }
}

extern "C" void kernel_launch(void* const* d_in, const int* in_sizes, int n_in,
                              void* d_out, int out_size, void* d_ws, size_t ws_size,
                              hipStream_t stream) {
    const float* pos          = (const float*)d_in[0];
    const int* node_type_edge = (const int*)d_in[1];
    const int* padding_mask   = (const int*)d_in[2];
    const int* mask_aa        = (const int*)d_in[3];
    const int* mask_pos       = (const int*)d_in[4];
    const int* time_pos       = (const int*)d_in[5];
    const float* means        = (const float*)d_in[6];
    const float* stds         = (const float*)d_in[7];
    const float* mul_w        = (const float*)d_in[8];
    const float* bias_w       = (const float*)d_in[9];
    const float* proj_w       = (const float*)d_in[10];
    const float* proj_b       = (const float*)d_in[11];
    const float* t_w1         = (const float*)d_in[12];
    const float* t_b1         = (const float*)d_in[13];
    const float* t_w2         = (const float*)d_in[14];
    const float* t_b2         = (const float*)d_in[15];

    float* out       = (float*)d_out;
    float* out_ef    = out;                                        // B*N*N*K
    float* out_merge = out + (size_t)BB * NN * NN * KK;            // B*N*E
    float* out_dp    = out_merge + (size_t)BB * NN * EE;           // B*N*N*3

    edge_fused_kernel<<<BB * NN, 256, 0, stream>>>(
        pos, node_type_edge, padding_mask, mask_aa, mask_pos, time_pos,
        means, stds, mul_w, bias_w, proj_w, proj_b,
        t_w1, t_b1, t_w2, t_b2,
        out_ef, out_merge, out_dp);
}